// Round 7
// baseline (199.419 us; speedup 1.0000x reference)
//
#include <hip/hip_runtime.h>

#define NN 384
#define HH 32
#define MM 50

__device__ __forceinline__ float fastRcp(float x) { return __builtin_amdgcn_rcpf(x); }

// Closed-form cardinal cubic B-spline features for the efficient-kan uniform
// grid: GRID_SIZE=5, SPLINE_ORDER=3, h=0.4, knots g[c]=(c-3)*h-1, c=0..11.
// Valid domain x in [-2.2, 2.2); outside -> zero basis (s=0), kb=100 sentinel.
__device__ __forceinline__ void featEval(float x, float& sil, int& kb, float b[4]) {
  sil = x * fastRcp(1.0f + __expf(-x));           // silu
  const float u  = (x + 1.0f) * 2.5f;
  const float fu = floorf(u);
  const bool valid = (fu >= -3.0f) && (fu <= 7.0f);
  const float s = valid ? (1.0f / 6.0f) : 0.0f;
  kb = valid ? (int)fu : 100;
  const float tt = u - fu;
  const float t2 = tt * tt, t3 = t2 * tt, omt = 1.0f - tt;
  b[0] = omt * omt * omt * s;
  b[1] = (3.0f * t3 - 6.0f * t2 + 4.0f) * s;
  b[2] = (-3.0f * t3 + 3.0f * t2 + 3.0f * tt + 1.0f) * s;
  b[3] = t3 * s;
}

__device__ __forceinline__ float waveReduce(float v) {
#pragma unroll
  for (int off = 32; off > 0; off >>= 1) v += __shfl_down(v, off);
  return v;
}

__device__ __forceinline__ float dot4(float4 a, float4 b) {
  float r = a.x * b.x;
  r = fmaf(a.y, b.y, r);
  r = fmaf(a.z, b.z, r);
  r = fmaf(a.w, b.w, r);
  return r;
}

// Stage A: layer-1 decomposition for all 3 modalities. Grid (385, 3, 2):
// blocks (i<384, m, half) compute 50 outputs of the A-half (half=0, weight
// cols 0..31) or B-half (half=1, cols 32..63) for row i of modality m; block
// (384, 0, 0) computes the fusion weights. Also zeroes the per-row arrival
// counters used by scoreRow's last-arriver tail.
__global__ __launch_bounds__(384) void stageA_kernel(
    const float* __restrict__ x, const float* __restrict__ y, const float* __restrict__ tg,
    const float* __restrict__ xbw, const float* __restrict__ xsw,
    const float* __restrict__ ybw, const float* __restrict__ ysw,
    const float* __restrict__ tbw, const float* __restrict__ tsw,
    const float* __restrict__ f1bw, const float* __restrict__ f1sw,
    const float* __restrict__ f2bw, const float* __restrict__ f2sw,
    float* __restrict__ A, float* __restrict__ Bt, float* __restrict__ wout,
    unsigned* __restrict__ ctr)
{
  const int tid = threadIdx.x;
  const int lane = tid & 63, w = tid >> 6;
  const int i = blockIdx.x;
  const int m = blockIdx.y;
  const int half = blockIdx.z;

  if (i < NN) {
    // ---------------- kanAB path ----------------
    __shared__ float bas[HH * 8];   // dense basis, bas[d*8+k]
    __shared__ float sil[HH];
    const float* q  = (m == 0) ? x   : ((m == 1) ? y   : tg);
    const float* bw = (m == 0) ? xbw : ((m == 1) ? ybw : tbw);
    const float* sw = (m == 0) ? xsw : ((m == 1) ? ysw : tsw);
    const int cb = half * HH;       // weight column base for this half

    if (m == 0 && half == 0 && tid == 0) ctr[i] = 0u;   // reset arrival counter

    if (tid < HH * 8) bas[tid] = 0.0f;
    __syncthreads();
    if (tid < HH) {
      float b[4]; float s; int kb;
      featEval(q[i * HH + tid], s, kb, b);   // features are q[i] for BOTH halves
      sil[tid] = s;
#pragma unroll
      for (int r = 0; r < 4; ++r) {
        const int k = kb + r;
        if ((unsigned)k < 8u) bas[tid * 8 + k] = b[r];
      }
    }
    __syncthreads();

    const float4* bas4 = (const float4*)bas;
    const float4 bb = bas4[lane];
    for (int o = w; o < MM; o += 6) {
      const float4* sp4 = (const float4*)(sw + ((size_t)(o * 2 * HH + cb) << 3));
      float acc = dot4(sp4[lane], bb);
      if (lane < HH)
        acc = fmaf(bw[o * 2 * HH + cb + lane], sil[lane], acc);
      acc = waveReduce(acc);
      if (lane == 0) {
        if (half == 0) A[((size_t)m * NN + i) * MM + o] = acc;
        else           Bt[((size_t)m * MM + o) * NN + i] = acc;
      }
    }
    return;
  }

  // ---------------- fusion path (block (384,0,0) only) ----------------
  if (m != 0 || half != 0) return;
  {
    __shared__ float4 part4[3][8][16];
    __shared__ float sil96[96];
    __shared__ float bas768[96 * 8];
    __shared__ float z1[MM];
    __shared__ float sil2[MM];
    __shared__ float bas400[MM * 8];
    __shared__ float s3[3];

    // phase A: column means (float4-vectorized, 16-way split)
    {
      const int mm = tid >> 7;
      const int sub = tid & 127;
      const int q4 = sub >> 4;
      const int prt = sub & 15;
      const float* src = (mm == 0) ? x : ((mm == 1) ? y : tg);
      const float4* s4 = (const float4*)src;
      float4 a = make_float4(0.f, 0.f, 0.f, 0.f);
      for (int r = prt; r < NN; r += 16) {
        const float4 v = s4[r * 8 + q4];
        a.x += v.x; a.y += v.y; a.z += v.z; a.w += v.w;
      }
      part4[mm][q4][prt] = a;
    }
    for (int idx = tid; idx < 96 * 8; idx += 384) bas768[idx] = 0.0f;
    for (int idx = tid; idx < MM * 8; idx += 384) bas400[idx] = 0.0f;
    __syncthreads();

    // phase B: finish means, build sil96 + dense basis bas768
    if (tid < 96) {
      const int mm = tid >> 5, col = tid & 31;
      const int q4 = col >> 2, comp = col & 3;
      const float* pp = (const float*)&part4[mm][q4][0];
      float v = 0.0f;
#pragma unroll
      for (int prt = 0; prt < 16; ++prt) v += pp[prt * 4 + comp];
      const float fv = v * (1.0f / NN);
      float b[4]; float s; int kb;
      featEval(fv, s, kb, b);
      sil96[tid] = s;
#pragma unroll
      for (int r = 0; r < 4; ++r) {
        const int k = kb + r;
        if ((unsigned)k < 8u) bas768[tid * 8 + k] = b[r];
      }
    }
    __syncthreads();

    // layer 1: 50 outputs, wave-per-output contiguous float4 dot
    {
      const float4* bas4 = (const float4*)bas768;
      for (int o = w; o < MM; o += 6) {
        const float4* sp4 = (const float4*)(f1sw + (size_t)o * (96 * 8));
        float acc = 0.0f;
#pragma unroll
        for (int r = 0; r < 3; ++r)
          acc += dot4(sp4[lane + 64 * r], bas4[lane + 64 * r]);
#pragma unroll
        for (int r = 0; r < 2; ++r) {
          const int e = lane + 64 * r;
          if (e < 96) acc = fmaf(f1bw[o * 96 + e], sil96[e], acc);
        }
        acc = waveReduce(acc);
        if (lane == 0) z1[o] = acc;
      }
    }
    __syncthreads();

    // hidden activation features
    if (tid < MM) {
      float b[4]; float s; int kb;
      featEval(z1[tid], s, kb, b);
      sil2[tid] = s;
#pragma unroll
      for (int r = 0; r < 4; ++r) {
        const int k = kb + r;
        if ((unsigned)k < 8u) bas400[tid * 8 + k] = b[r];
      }
    }
    __syncthreads();

    // layer 2: 3 outputs, one wave each
    if (w < 3) {
      const float4* bas4 = (const float4*)bas400;
      const float4* sp4 = (const float4*)(f2sw + (size_t)w * (MM * 8));
      float acc = 0.0f;
#pragma unroll
      for (int r = 0; r < 2; ++r) {
        const int f = lane + 64 * r;
        if (f < MM * 2) acc += dot4(sp4[f], bas4[f]);
      }
      if (lane < MM) acc = fmaf(f2bw[w * MM + lane], sil2[lane], acc);
      acc = waveReduce(acc);
      if (lane == 0) s3[w] = acc;
    }
    __syncthreads();

    if (tid == 0) {
      const float mx = fmaxf(s3[0], fmaxf(s3[1], s3[2]));
      const float e0 = __expf(s3[0] - mx), e1 = __expf(s3[1] - mx), e2 = __expf(s3[2] - mx);
      const float inv = fastRcp(e0 + e1 + e2);
      wout[0] = e0 * inv; wout[1] = e1 * inv; wout[2] = e2 * inv;
    }
  }
}

// scoreRow: grid (384 rows, 3 modalities), 384 threads (one per column j).
// Each block computes Sp[m][i][j] = kanLayer2_m(A_m[i]+B_m[j]) with a 2-deep
// software-pipelined k-loop, publishes its plane-row, then the LAST arriving
// block for row i (device-scope counter) runs the row tail: weighted fuse +
// bias, softmax, @target, two final 32->32 KAN layers. Output is bitwise
// identical regardless of which block runs the tail.
__global__ __launch_bounds__(384, 6) void scoreRow_kernel(
    const float* __restrict__ A, const float* __restrict__ Bt,
    const float* __restrict__ x2bw, const float* __restrict__ y2bw, const float* __restrict__ t2bw,
    const float* __restrict__ x2sw, const float* __restrict__ y2sw, const float* __restrict__ t2sw,
    const float* __restrict__ wv, const float* __restrict__ bias,
    const float* __restrict__ tg,
    const float* __restrict__ l1bw, const float* __restrict__ l1sw,
    const float* __restrict__ l2bw, const float* __restrict__ l2sw,
    float* __restrict__ Sp, unsigned* __restrict__ ctr, float* __restrict__ out)
{
  __shared__ float sA[MM];
  __shared__ float sBW[MM];
  __shared__ float pad[MM][14];     // spline weights zero-padded +3 each side
  __shared__ float4 coef[MM][13];   // per-cell cubic coeffs (a0,a1,a2,a3)
  __shared__ unsigned sdone;
  // tail storage
  __shared__ float p[NN];
  __shared__ float redm[6], reds[6];
  __shared__ float part[12][HH];
  __shared__ float ta[HH];
  __shared__ float basF[HH * 8];
  __shared__ float silF[HH];
  __shared__ float y1v[HH];

  const int tid = threadIdx.x;
  const int lane = tid & 63, w = tid >> 6;
  const int i = blockIdx.x;
  const int m = blockIdx.y;
  const float* bsrc = (m == 0) ? x2bw : ((m == 1) ? y2bw : t2bw);
  const float* ssrc = (m == 0) ? x2sw : ((m == 1) ? y2sw : t2sw);

  for (int idx = tid; idx < MM * 6; idx += 384) {
    const int kk = idx / 6, r = idx - kk * 6;
    pad[kk][(r < 3) ? r : (r + 8)] = 0.0f;
  }
  for (int idx = tid; idx < MM * 8; idx += 384) {
    pad[idx >> 3][3 + (idx & 7)] = ssrc[idx];
  }
  if (tid < MM) {
    sA[tid]  = A[((size_t)m * NN + i) * MM + tid];
    sBW[tid] = bsrc[tid];
  }
  __syncthreads();

  // fold spline weights through the cardinal-basis matrix -> cubic coeffs
  for (int idx = tid; idx < MM * 11; idx += 384) {
    const int k = idx / 11, cm1 = idx - k * 11;   // cell-1: 0..10
    const float* bp = &pad[k][cm1];
    const float p0 = bp[0], p1 = bp[1], p2 = bp[2], p3 = bp[3];
    const float a0 = (p0 + 4.0f * p1 + p2) * (1.0f / 6.0f);
    const float a1 = (p2 - p0) * 0.5f;
    const float a2 = (p0 - 2.0f * p1 + p2) * 0.5f;
    const float a3 = (p3 - p0) * (1.0f / 6.0f) + (p1 - p2) * 0.5f;
    coef[k][cm1 + 1] = make_float4(a0, a1, a2, a3);
  }
  if (tid < MM * 2) {
    coef[tid >> 1][(tid & 1) * 12] = make_float4(0.f, 0.f, 0.f, 0.f);
  }
  __syncthreads();

  // ---- main score loop: 2-deep software pipeline over k ----
  const float* BtBase = Bt + (size_t)m * MM * NN + tid;
  float acc0 = 0.0f, acc1 = 0.0f;
  float za = BtBase[0];
  float zb = BtBase[NN];
#pragma unroll 5
  for (int k = 0; k < MM; k += 2) {
    float zc = 0.0f, zd = 0.0f;
    if (k + 3 < MM) {                       // prefetch next pair under compute
      zc = BtBase[(size_t)(k + 2) * NN];
      zd = BtBase[(size_t)(k + 3) * NN];
    }
    {
      const float z0 = sA[k] + za;
      const float u = fmaf(z0, 2.5f, 2.5f);
      const float fu = floorf(u);
      const float t = u - fu;
      const int cc = (int)(fminf(fmaxf(fu, -4.0f), 8.0f)) + 4;
      const float4 C = coef[k][cc];
      acc0 += fmaf(t, fmaf(t, fmaf(t, C.w, C.z), C.y), C.x);
      const float sg = fastRcp(1.0f + __expf(-z0));
      acc0 = fmaf(z0 * sg, sBW[k], acc0);
    }
    {
      const float z1 = sA[k + 1] + zb;
      const float u = fmaf(z1, 2.5f, 2.5f);
      const float fu = floorf(u);
      const float t = u - fu;
      const int cc = (int)(fminf(fmaxf(fu, -4.0f), 8.0f)) + 4;
      const float4 C = coef[k + 1][cc];
      acc1 += fmaf(t, fmaf(t, fmaf(t, C.w, C.z), C.y), C.x);
      const float sg = fastRcp(1.0f + __expf(-z1));
      acc1 = fmaf(z1 * sg, sBW[k + 1], acc1);
    }
    za = zc; zb = zd;
  }
  Sp[((size_t)m * NN + i) * NN + tid] = acc0 + acc1;

  // ---- publish + last-arriver election ----
  __threadfence();                 // make this block's Sp row visible device-wide
  __syncthreads();
  if (tid == 0) sdone = atomicAdd(&ctr[i], 1u);
  __syncthreads();
  if (sdone != 2u) return;         // not the last arriver
  __threadfence();                 // acquire: other planes' writes now visible

  // ================= row tail (runs in exactly one block per row) =========
  float stot = bias[0];
  stot = fmaf(wv[0], Sp[(size_t)i * NN + tid], stot);
  stot = fmaf(wv[1], Sp[((size_t)NN + i) * NN + tid], stot);
  stot = fmaf(wv[2], Sp[((size_t)2 * NN + i) * NN + tid], stot);

  // ---- row softmax ----
  float v = stot;
#pragma unroll
  for (int off = 32; off > 0; off >>= 1) v = fmaxf(v, __shfl_down(v, off));
  if (lane == 0) redm[w] = v;
  __syncthreads();
  float mx = redm[0];
#pragma unroll
  for (int ww = 1; ww < 6; ++ww) mx = fmaxf(mx, redm[ww]);
  const float e = __expf(stot - mx);
  p[tid] = e;
  float sv = e;
#pragma unroll
  for (int off = 32; off > 0; off >>= 1) sv += __shfl_down(sv, off);
  if (lane == 0) reds[w] = sv;
  __syncthreads();
  const float ssum = reds[0] + reds[1] + reds[2] + reds[3] + reds[4] + reds[5];
  const float inv = 1.0f / ssum;

  // ---- target_att row ----
  const int d = tid & 31, g = tid >> 5;
  float acc2 = 0.0f;
  for (int s2 = 0; s2 < 32; ++s2) {
    const int j = g * 32 + s2;
    acc2 = fmaf(p[j], tg[j * HH + d], acc2);
  }
  part[g][d] = acc2;
  if (tid < HH * 8) basF[tid] = 0.0f;
  __syncthreads();
  if (tid < HH) {
    float a = 0.0f;
#pragma unroll
    for (int gg = 0; gg < 12; ++gg) a += part[gg][tid];
    ta[tid] = a * inv;
  }
  __syncthreads();

  // ---- final KAN layer 1 (32 -> 32, relu) via float4 wave-dot ----
  if (tid < HH) {
    float b[4]; float s; int kb;
    featEval(ta[tid], s, kb, b);
    silF[tid] = s;
#pragma unroll
    for (int r = 0; r < 4; ++r) {
      const int k = kb + r;
      if ((unsigned)k < 8u) basF[tid * 8 + k] = b[r];
    }
  }
  __syncthreads();
  {
    const float4 bb = ((const float4*)basF)[lane];
    for (int o = w; o < HH; o += 6) {
      const float4* sp4 = (const float4*)(l1sw + ((size_t)o << 8));
      float acc = dot4(sp4[lane], bb);
      if (lane < HH) acc = fmaf(l1bw[o * HH + lane], silF[lane], acc);
      acc = waveReduce(acc);
      if (lane == 0) y1v[o] = fmaxf(acc, 0.0f);
    }
  }
  __syncthreads();
  if (tid < HH * 8) basF[tid] = 0.0f;
  __syncthreads();
  if (tid < HH) {
    float b[4]; float s; int kb;
    featEval(y1v[tid], s, kb, b);
    silF[tid] = s;
#pragma unroll
    for (int r = 0; r < 4; ++r) {
      const int k = kb + r;
      if ((unsigned)k < 8u) basF[tid * 8 + k] = b[r];
    }
  }
  __syncthreads();
  // ---- final KAN layer 2 (32 -> 32, relu) ----
  {
    const float4 bb = ((const float4*)basF)[lane];
    for (int o = w; o < HH; o += 6) {
      const float4* sp4 = (const float4*)(l2sw + ((size_t)o << 8));
      float acc = dot4(sp4[lane], bb);
      if (lane < HH) acc = fmaf(l2bw[o * HH + lane], silF[lane], acc);
      acc = waveReduce(acc);
      if (lane == 0) out[i * HH + o] = fmaxf(acc, 0.0f);
    }
  }
}

extern "C" void kernel_launch(void* const* d_in, const int* in_sizes, int n_in,
                              void* d_out, int out_size, void* d_ws, size_t ws_size,
                              hipStream_t stream)
{
  const float* x    = (const float*)d_in[0];
  const float* y    = (const float*)d_in[1];
  const float* tg   = (const float*)d_in[2];
  const float* bias = (const float*)d_in[3];
  const float* x1bw = (const float*)d_in[4];
  const float* x1sw = (const float*)d_in[5];
  const float* x2bw = (const float*)d_in[6];
  const float* x2sw = (const float*)d_in[7];
  const float* y1bw = (const float*)d_in[8];
  const float* y1sw = (const float*)d_in[9];
  const float* y2bw = (const float*)d_in[10];
  const float* y2sw = (const float*)d_in[11];
  const float* t1bw = (const float*)d_in[12];
  const float* t1sw = (const float*)d_in[13];
  const float* t2bw = (const float*)d_in[14];
  const float* t2sw = (const float*)d_in[15];
  const float* f1bw = (const float*)d_in[16];
  const float* f1sw = (const float*)d_in[17];
  const float* f2bw = (const float*)d_in[18];
  const float* f2sw = (const float*)d_in[19];
  const float* l1bw = (const float*)d_in[20];
  const float* l1sw = (const float*)d_in[21];
  const float* l2bw = (const float*)d_in[22];
  const float* l2sw = (const float*)d_in[23];
  float* out = (float*)d_out;

  float* ws = (float*)d_ws;
  float* A   = ws;                          // [3][384][50]
  float* Bt  = ws + 3 * NN * MM;            // [3][50][384]
  float* wv  = ws + 6 * NN * MM;            // [3] (+1 pad)
  unsigned* ctr = (unsigned*)(ws + 6 * NN * MM + 4);   // [384]
  float* Sp  = ws + 6 * NN * MM + 4 + NN;   // [3][384][384]

  stageA_kernel<<<dim3(NN + 1, 3, 2), 384, 0, stream>>>(
      x, y, tg, x1bw, x1sw, y1bw, y1sw, t1bw, t1sw,
      f1bw, f1sw, f2bw, f2sw, A, Bt, wv, ctr);
  scoreRow_kernel<<<dim3(NN, 3), 384, 0, stream>>>(
      A, Bt, x2bw, y2bw, t2bw, x2sw, y2sw, t2sw,
      wv, bias, tg, l1bw, l1sw, l2bw, l2sw, Sp, ctr, out);
}

// Round 8
// 52.227 us; speedup vs baseline: 3.8183x; 3.8183x over previous
//
#include <hip/hip_runtime.h>

#define NN 384
#define HH 32
#define MM 50

__device__ __forceinline__ float fastRcp(float x) { return __builtin_amdgcn_rcpf(x); }

// Closed-form cardinal cubic B-spline features for the efficient-kan uniform
// grid: GRID_SIZE=5, SPLINE_ORDER=3, h=0.4, knots g[c]=(c-3)*h-1, c=0..11.
// Valid domain x in [-2.2, 2.2); outside -> zero basis (s=0), kb=100 sentinel.
__device__ __forceinline__ void featEval(float x, float& sil, int& kb, float b[4]) {
  sil = x * fastRcp(1.0f + __expf(-x));           // silu
  const float u  = (x + 1.0f) * 2.5f;
  const float fu = floorf(u);
  const bool valid = (fu >= -3.0f) && (fu <= 7.0f);
  const float s = valid ? (1.0f / 6.0f) : 0.0f;
  kb = valid ? (int)fu : 100;
  const float tt = u - fu;
  const float t2 = tt * tt, t3 = t2 * tt, omt = 1.0f - tt;
  b[0] = omt * omt * omt * s;
  b[1] = (3.0f * t3 - 6.0f * t2 + 4.0f) * s;
  b[2] = (-3.0f * t3 + 3.0f * t2 + 3.0f * tt + 1.0f) * s;
  b[3] = t3 * s;
}

__device__ __forceinline__ float waveReduce(float v) {
#pragma unroll
  for (int off = 32; off > 0; off >>= 1) v += __shfl_down(v, off);
  return v;
}

__device__ __forceinline__ float dot4(float4 a, float4 b) {
  float r = a.x * b.x;
  r = fmaf(a.y, b.y, r);
  r = fmaf(a.z, b.z, r);
  r = fmaf(a.w, b.w, r);
  return r;
}

// Stage A: layer-1 decomposition for all 3 modalities, 2 rows per block.
// Grid (193, 3, 2): blocks (bi<192, m, half) compute 50 outputs of the A-half
// (half=0, weight cols 0..31) or B-half (half=1, cols 32..63) for rows
// {2bi, 2bi+1} of modality m; block (192, 0, 0) computes the fusion weights.
// Each output is a wave-level float4 dot: ONE global dwordx4 weight load
// amortized over BOTH rows' bases (halves L2 traffic, doubles ILP).
__global__ __launch_bounds__(384) void stageA_kernel(
    const float* __restrict__ x, const float* __restrict__ y, const float* __restrict__ tg,
    const float* __restrict__ xbw, const float* __restrict__ xsw,
    const float* __restrict__ ybw, const float* __restrict__ ysw,
    const float* __restrict__ tbw, const float* __restrict__ tsw,
    const float* __restrict__ f1bw, const float* __restrict__ f1sw,
    const float* __restrict__ f2bw, const float* __restrict__ f2sw,
    float* __restrict__ A, float* __restrict__ Bt, float* __restrict__ wout)
{
  const int tid = threadIdx.x;
  const int lane = tid & 63, w = tid >> 6;
  const int bi = blockIdx.x;
  const int m = blockIdx.y;
  const int half = blockIdx.z;

  if (bi < NN / 2) {
    // ---------------- kanAB path (2 rows) ----------------
    __shared__ float bas[2][HH * 8];   // dense basis per row, bas[r][d*8+k]
    __shared__ float sil[2][HH];
    const int i0 = bi * 2;
    const float* q  = (m == 0) ? x   : ((m == 1) ? y   : tg);
    const float* bw = (m == 0) ? xbw : ((m == 1) ? ybw : tbw);
    const float* sw = (m == 0) ? xsw : ((m == 1) ? ysw : tsw);
    const int cb = half * HH;       // weight column base for this half

    for (int idx = tid; idx < 2 * HH * 8; idx += 384) (&bas[0][0])[idx] = 0.0f;
    __syncthreads();
    if (tid < 2 * HH) {
      const int r = tid >> 5, d = tid & 31;
      float b[4]; float s; int kb;
      featEval(q[(i0 + r) * HH + d], s, kb, b);
      sil[r][d] = s;
#pragma unroll
      for (int rr = 0; rr < 4; ++rr) {
        const int k = kb + rr;
        if ((unsigned)k < 8u) bas[r][d * 8 + k] = b[rr];
      }
    }
    __syncthreads();

    const float4 bb0 = ((const float4*)&bas[0][0])[lane];
    const float4 bb1 = ((const float4*)&bas[1][0])[lane];
    const float sl0 = (lane < HH) ? sil[0][lane] : 0.0f;
    const float sl1 = (lane < HH) ? sil[1][lane] : 0.0f;
    for (int o = w; o < MM; o += 6) {
      const float4 wv4 = ((const float4*)(sw + ((size_t)(o * 2 * HH + cb) << 3)))[lane];
      const float bwv = (lane < HH) ? bw[o * 2 * HH + cb + lane] : 0.0f;
      float a0 = dot4(wv4, bb0);
      float a1 = dot4(wv4, bb1);
      a0 = fmaf(bwv, sl0, a0);
      a1 = fmaf(bwv, sl1, a1);
      a0 = waveReduce(a0);
      a1 = waveReduce(a1);
      if (lane == 0) {
        if (half == 0) {
          A[((size_t)m * NN + i0) * MM + o]     = a0;
          A[((size_t)m * NN + i0 + 1) * MM + o] = a1;
        } else {
          Bt[((size_t)m * MM + o) * NN + i0]     = a0;
          Bt[((size_t)m * MM + o) * NN + i0 + 1] = a1;
        }
      }
    }
    return;
  }

  // ---------------- fusion path (block (192,0,0) only) ----------------
  if (m != 0 || half != 0) return;
  {
    __shared__ float4 part4[3][8][16];
    __shared__ float sil96[96];
    __shared__ float bas768[96 * 8];
    __shared__ float z1[MM];
    __shared__ float sil2[MM];
    __shared__ float bas400[MM * 8];
    __shared__ float s3[3];

    // phase A: column means (float4-vectorized, 16-way split)
    {
      const int mm = tid >> 7;
      const int sub = tid & 127;
      const int q4 = sub >> 4;
      const int prt = sub & 15;
      const float* src = (mm == 0) ? x : ((mm == 1) ? y : tg);
      const float4* s4 = (const float4*)src;
      float4 a = make_float4(0.f, 0.f, 0.f, 0.f);
      for (int r = prt; r < NN; r += 16) {
        const float4 v = s4[r * 8 + q4];
        a.x += v.x; a.y += v.y; a.z += v.z; a.w += v.w;
      }
      part4[mm][q4][prt] = a;
    }
    for (int idx = tid; idx < 96 * 8; idx += 384) bas768[idx] = 0.0f;
    for (int idx = tid; idx < MM * 8; idx += 384) bas400[idx] = 0.0f;
    __syncthreads();

    // phase B: finish means, build sil96 + dense basis bas768
    if (tid < 96) {
      const int mm = tid >> 5, col = tid & 31;
      const int q4 = col >> 2, comp = col & 3;
      const float* pp = (const float*)&part4[mm][q4][0];
      float v = 0.0f;
#pragma unroll
      for (int prt = 0; prt < 16; ++prt) v += pp[prt * 4 + comp];
      const float fv = v * (1.0f / NN);
      float b[4]; float s; int kb;
      featEval(fv, s, kb, b);
      sil96[tid] = s;
#pragma unroll
      for (int r = 0; r < 4; ++r) {
        const int k = kb + r;
        if ((unsigned)k < 8u) bas768[tid * 8 + k] = b[r];
      }
    }
    __syncthreads();

    // layer 1: 50 outputs, wave-per-output contiguous float4 dot
    {
      const float4* bas4 = (const float4*)bas768;
      for (int o = w; o < MM; o += 6) {
        const float4* sp4 = (const float4*)(f1sw + (size_t)o * (96 * 8));
        float acc = 0.0f;
#pragma unroll
        for (int r = 0; r < 3; ++r)
          acc += dot4(sp4[lane + 64 * r], bas4[lane + 64 * r]);
#pragma unroll
        for (int r = 0; r < 2; ++r) {
          const int e = lane + 64 * r;
          if (e < 96) acc = fmaf(f1bw[o * 96 + e], sil96[e], acc);
        }
        acc = waveReduce(acc);
        if (lane == 0) z1[o] = acc;
      }
    }
    __syncthreads();

    // hidden activation features
    if (tid < MM) {
      float b[4]; float s; int kb;
      featEval(z1[tid], s, kb, b);
      sil2[tid] = s;
#pragma unroll
      for (int r = 0; r < 4; ++r) {
        const int k = kb + r;
        if ((unsigned)k < 8u) bas400[tid * 8 + k] = b[r];
      }
    }
    __syncthreads();

    // layer 2: 3 outputs, one wave each
    if (w < 3) {
      const float4* bas4 = (const float4*)bas400;
      const float4* sp4 = (const float4*)(f2sw + (size_t)w * (MM * 8));
      float acc = 0.0f;
#pragma unroll
      for (int r = 0; r < 2; ++r) {
        const int f = lane + 64 * r;
        if (f < MM * 2) acc += dot4(sp4[f], bas4[f]);
      }
      if (lane < MM) acc = fmaf(f2bw[w * MM + lane], sil2[lane], acc);
      acc = waveReduce(acc);
      if (lane == 0) s3[w] = acc;
    }
    __syncthreads();

    if (tid == 0) {
      const float mx = fmaxf(s3[0], fmaxf(s3[1], s3[2]));
      const float e0 = __expf(s3[0] - mx), e1 = __expf(s3[1] - mx), e2 = __expf(s3[2] - mx);
      const float inv = fastRcp(e0 + e1 + e2);
      wout[0] = e0 * inv; wout[1] = e1 * inv; wout[2] = e2 * inv;
    }
  }
}

// Per-modality layer-2 KAN over all pairs, 2 rows per block: grid (192, 3),
// 384 threads (one per column j). Sp[m][i][j] = kanLayer2_m(A_m[i]+B_m[j]).
// Each Bt load feeds evals for BOTH rows (latency amortized, 4 independent
// acc chains); spline via per-cell Horner coefficient table in LDS (cells
// 1..11 real, 0/12 zero sentinels; k is wave-uniform so the coef gather is
// a <=13-address, ~2-way-bank read -> near-free).
__global__ __launch_bounds__(384) void score_kernel(
    const float* __restrict__ A, const float* __restrict__ Bt,
    const float* __restrict__ x2bw, const float* __restrict__ y2bw, const float* __restrict__ t2bw,
    const float* __restrict__ x2sw, const float* __restrict__ y2sw, const float* __restrict__ t2sw,
    float* __restrict__ Sp)
{
  __shared__ float sA[2][MM];
  __shared__ float sBW[MM];
  __shared__ float pad[MM][14];     // spline weights zero-padded +3 each side
  __shared__ float4 coef[MM][13];   // per-cell cubic coeffs (a0,a1,a2,a3)
  const int tid = threadIdx.x;
  const int ii = blockIdx.x;
  const int m = blockIdx.y;
  const int i0 = ii * 2;
  const float* bsrc = (m == 0) ? x2bw : ((m == 1) ? y2bw : t2bw);
  const float* ssrc = (m == 0) ? x2sw : ((m == 1) ? y2sw : t2sw);

  for (int idx = tid; idx < MM * 6; idx += 384) {
    const int kk = idx / 6, r = idx - kk * 6;
    pad[kk][(r < 3) ? r : (r + 8)] = 0.0f;
  }
  for (int idx = tid; idx < MM * 8; idx += 384) {
    pad[idx >> 3][3 + (idx & 7)] = ssrc[idx];
  }
  if (tid < 2 * MM) {
    const int r = (tid >= MM) ? 1 : 0;
    const int k = tid - r * MM;
    sA[r][k] = A[((size_t)m * NN + i0 + r) * MM + k];
    if (r == 0) sBW[k] = bsrc[k];
  }
  __syncthreads();

  // fold spline weights through the cardinal-basis matrix -> cubic coeffs
  for (int idx = tid; idx < MM * 11; idx += 384) {
    const int k = idx / 11, cm1 = idx - k * 11;   // cell-1: 0..10
    const float* bp = &pad[k][cm1];
    const float p0 = bp[0], p1 = bp[1], p2 = bp[2], p3 = bp[3];
    const float a0 = (p0 + 4.0f * p1 + p2) * (1.0f / 6.0f);
    const float a1 = (p2 - p0) * 0.5f;
    const float a2 = (p0 - 2.0f * p1 + p2) * 0.5f;
    const float a3 = (p3 - p0) * (1.0f / 6.0f) + (p1 - p2) * 0.5f;
    coef[k][cm1 + 1] = make_float4(a0, a1, a2, a3);
  }
  if (tid < MM * 2) {
    coef[tid >> 1][(tid & 1) * 12] = make_float4(0.f, 0.f, 0.f, 0.f);
  }
  __syncthreads();

  const float* BtBase = Bt + (size_t)m * MM * NN + tid;
  float acc00 = 0.0f, acc01 = 0.0f, acc10 = 0.0f, acc11 = 0.0f;
  float za = BtBase[0];
  float zb = BtBase[NN];

#define KAN_EVAL(zz, kk, accv)                                          \
  {                                                                     \
    const float z_ = (zz);                                              \
    const float u_ = fmaf(z_, 2.5f, 2.5f);                              \
    const float fu_ = floorf(u_);                                       \
    const float t_ = u_ - fu_;                                          \
    const int cc_ = (int)(fminf(fmaxf(fu_, -4.0f), 8.0f)) + 4;          \
    const float4 C_ = coef[kk][cc_];                                    \
    accv += fmaf(t_, fmaf(t_, fmaf(t_, C_.w, C_.z), C_.y), C_.x);       \
    const float sg_ = fastRcp(1.0f + __expf(-z_));                      \
    accv = fmaf(z_ * sg_, sBW[kk], accv);                               \
  }

#pragma unroll 5
  for (int k = 0; k < MM; k += 2) {
    float zc = 0.0f, zd = 0.0f;
    if (k + 3 < MM) {                       // prefetch next pair under compute
      zc = BtBase[(size_t)(k + 2) * NN];
      zd = BtBase[(size_t)(k + 3) * NN];
    }
    KAN_EVAL(sA[0][k] + za,     k,     acc00);
    KAN_EVAL(sA[1][k] + za,     k,     acc10);
    KAN_EVAL(sA[0][k + 1] + zb, k + 1, acc01);
    KAN_EVAL(sA[1][k + 1] + zb, k + 1, acc11);
    za = zc; zb = zd;
  }
#undef KAN_EVAL

  Sp[((size_t)m * NN + i0) * NN + tid]     = acc00 + acc01;
  Sp[((size_t)m * NN + i0 + 1) * NN + tid] = acc10 + acc11;
}

// Row kernel: weighted fuse of 3 score planes + bias, row softmax, @target,
// two final 32->32 KAN layers (relu) via float4 wave-dots. One block per row.
__global__ __launch_bounds__(384) void row_kernel(
    const float* __restrict__ Sp, const float* __restrict__ wv, const float* __restrict__ bias,
    const float* __restrict__ tg,
    const float* __restrict__ l1bw, const float* __restrict__ l1sw,
    const float* __restrict__ l2bw, const float* __restrict__ l2sw,
    float* __restrict__ out)
{
  __shared__ float p[NN];
  __shared__ float redm[6], reds[6];
  __shared__ float part[12][HH];
  __shared__ float ta[HH];
  __shared__ float basF[HH * 8];
  __shared__ float silF[HH];
  __shared__ float y1v[HH];
  const int tid = threadIdx.x;
  const int lane = tid & 63, w = tid >> 6;
  const int i = blockIdx.x;

  float stot = bias[0];
  stot = fmaf(wv[0], Sp[(size_t)i * NN + tid], stot);
  stot = fmaf(wv[1], Sp[((size_t)NN + i) * NN + tid], stot);
  stot = fmaf(wv[2], Sp[((size_t)2 * NN + i) * NN + tid], stot);

  // ---- row softmax ----
  float v = stot;
#pragma unroll
  for (int off = 32; off > 0; off >>= 1) v = fmaxf(v, __shfl_down(v, off));
  if (lane == 0) redm[w] = v;
  __syncthreads();
  float mx = redm[0];
#pragma unroll
  for (int ww = 1; ww < 6; ++ww) mx = fmaxf(mx, redm[ww]);
  const float e = __expf(stot - mx);
  p[tid] = e;
  float sv = e;
#pragma unroll
  for (int off = 32; off > 0; off >>= 1) sv += __shfl_down(sv, off);
  if (lane == 0) reds[w] = sv;
  __syncthreads();
  const float ssum = reds[0] + reds[1] + reds[2] + reds[3] + reds[4] + reds[5];
  const float inv = 1.0f / ssum;

  // ---- target_att row ----
  const int d = tid & 31, g = tid >> 5;
  float acc2 = 0.0f;
  for (int s2 = 0; s2 < 32; ++s2) {
    const int j = g * 32 + s2;
    acc2 = fmaf(p[j], tg[j * HH + d], acc2);
  }
  part[g][d] = acc2;
  if (tid < HH * 8) basF[tid] = 0.0f;
  __syncthreads();
  if (tid < HH) {
    float a = 0.0f;
#pragma unroll
    for (int gg = 0; gg < 12; ++gg) a += part[gg][tid];
    ta[tid] = a * inv;
  }
  __syncthreads();

  // ---- final KAN layer 1 (32 -> 32, relu) via float4 wave-dot ----
  if (tid < HH) {
    float b[4]; float s; int kb;
    featEval(ta[tid], s, kb, b);
    silF[tid] = s;
#pragma unroll
    for (int r = 0; r < 4; ++r) {
      const int k = kb + r;
      if ((unsigned)k < 8u) basF[tid * 8 + k] = b[r];
    }
  }
  __syncthreads();
  {
    const float4 bb = ((const float4*)basF)[lane];
    for (int o = w; o < HH; o += 6) {
      const float4* sp4 = (const float4*)(l1sw + ((size_t)o << 8));
      float acc = dot4(sp4[lane], bb);
      if (lane < HH) acc = fmaf(l1bw[o * HH + lane], silF[lane], acc);
      acc = waveReduce(acc);
      if (lane == 0) y1v[o] = fmaxf(acc, 0.0f);
    }
  }
  __syncthreads();
  if (tid < HH * 8) basF[tid] = 0.0f;
  __syncthreads();
  if (tid < HH) {
    float b[4]; float s; int kb;
    featEval(y1v[tid], s, kb, b);
    silF[tid] = s;
#pragma unroll
    for (int r = 0; r < 4; ++r) {
      const int k = kb + r;
      if ((unsigned)k < 8u) basF[tid * 8 + k] = b[r];
    }
  }
  __syncthreads();
  // ---- final KAN layer 2 (32 -> 32, relu) ----
  {
    const float4 bb = ((const float4*)basF)[lane];
    for (int o = w; o < HH; o += 6) {
      const float4* sp4 = (const float4*)(l2sw + ((size_t)o << 8));
      float acc = dot4(sp4[lane], bb);
      if (lane < HH) acc = fmaf(l2bw[o * HH + lane], silF[lane], acc);
      acc = waveReduce(acc);
      if (lane == 0) out[i * HH + o] = fmaxf(acc, 0.0f);
    }
  }
}

extern "C" void kernel_launch(void* const* d_in, const int* in_sizes, int n_in,
                              void* d_out, int out_size, void* d_ws, size_t ws_size,
                              hipStream_t stream)
{
  const float* x    = (const float*)d_in[0];
  const float* y    = (const float*)d_in[1];
  const float* tg   = (const float*)d_in[2];
  const float* bias = (const float*)d_in[3];
  const float* x1bw = (const float*)d_in[4];
  const float* x1sw = (const float*)d_in[5];
  const float* x2bw = (const float*)d_in[6];
  const float* x2sw = (const float*)d_in[7];
  const float* y1bw = (const float*)d_in[8];
  const float* y1sw = (const float*)d_in[9];
  const float* y2bw = (const float*)d_in[10];
  const float* y2sw = (const float*)d_in[11];
  const float* t1bw = (const float*)d_in[12];
  const float* t1sw = (const float*)d_in[13];
  const float* t2bw = (const float*)d_in[14];
  const float* t2sw = (const float*)d_in[15];
  const float* f1bw = (const float*)d_in[16];
  const float* f1sw = (const float*)d_in[17];
  const float* f2bw = (const float*)d_in[18];
  const float* f2sw = (const float*)d_in[19];
  const float* l1bw = (const float*)d_in[20];
  const float* l1sw = (const float*)d_in[21];
  const float* l2bw = (const float*)d_in[22];
  const float* l2sw = (const float*)d_in[23];
  float* out = (float*)d_out;

  float* ws = (float*)d_ws;
  float* A  = ws;                          // [3][384][50]
  float* Bt = ws + 3 * NN * MM;            // [3][50][384]
  float* Sp = ws + 6 * NN * MM;            // [3][384][384]
  float* wv = Sp + 3 * NN * NN;            // [3]

  stageA_kernel<<<dim3(NN / 2 + 1, 3, 2), 384, 0, stream>>>(
      x, y, tg, x1bw, x1sw, y1bw, y1sw, t1bw, t1sw,
      f1bw, f1sw, f2bw, f2sw, A, Bt, wv);
  score_kernel<<<dim3(NN / 2, 3), 384, 0, stream>>>(A, Bt, x2bw, y2bw, t2bw,
                                                    x2sw, y2sw, t2sw, Sp);
  row_kernel<<<NN, 384, 0, stream>>>(Sp, wv, bias, tg, l1bw, l1sw, l2bw, l2sw, out);
}

// Round 9
// 46.252 us; speedup vs baseline: 4.3115x; 1.1292x over previous
//
#include <hip/hip_runtime.h>

#define NN 384
#define HH 32
#define MM 50

__device__ __forceinline__ float fastRcp(float x) { return __builtin_amdgcn_rcpf(x); }

// Closed-form cardinal cubic B-spline features for the efficient-kan uniform
// grid: GRID_SIZE=5, SPLINE_ORDER=3, h=0.4, knots g[c]=(c-3)*h-1, c=0..11.
// Valid domain x in [-2.2, 2.2); outside -> zero basis (s=0), kb=100 sentinel.
__device__ __forceinline__ void featEval(float x, float& sil, int& kb, float b[4]) {
  sil = x * fastRcp(1.0f + __expf(-x));           // silu
  const float u  = (x + 1.0f) * 2.5f;
  const float fu = floorf(u);
  const bool valid = (fu >= -3.0f) && (fu <= 7.0f);
  const float s = valid ? (1.0f / 6.0f) : 0.0f;
  kb = valid ? (int)fu : 100;
  const float tt = u - fu;
  const float t2 = tt * tt, t3 = t2 * tt, omt = 1.0f - tt;
  b[0] = omt * omt * omt * s;
  b[1] = (3.0f * t3 - 6.0f * t2 + 4.0f) * s;
  b[2] = (-3.0f * t3 + 3.0f * t2 + 3.0f * tt + 1.0f) * s;
  b[3] = t3 * s;
}

__device__ __forceinline__ float waveReduce(float v) {
#pragma unroll
  for (int off = 32; off > 0; off >>= 1) v += __shfl_down(v, off);
  return v;
}

__device__ __forceinline__ float dot4(float4 a, float4 b) {
  float r = a.x * b.x;
  r = fmaf(a.y, b.y, r);
  r = fmaf(a.z, b.z, r);
  r = fmaf(a.w, b.w, r);
  return r;
}

// Stage A: layer-1 decomposition for all 3 modalities. Grid (385, 3, 2):
// blocks (i<384, m, half) compute 50 outputs of the A-half (half=0, weight
// cols 0..31) or B-half (half=1, cols 32..63) for row i of modality m; block
// (384, 0, 0) computes the fusion weights. Every KAN output is a wave-level
// float4 dot product over a CONTIGUOUS weight span against a dense
// zero-filled basis vector in LDS.
__global__ __launch_bounds__(384) void stageA_kernel(
    const float* __restrict__ x, const float* __restrict__ y, const float* __restrict__ tg,
    const float* __restrict__ xbw, const float* __restrict__ xsw,
    const float* __restrict__ ybw, const float* __restrict__ ysw,
    const float* __restrict__ tbw, const float* __restrict__ tsw,
    const float* __restrict__ f1bw, const float* __restrict__ f1sw,
    const float* __restrict__ f2bw, const float* __restrict__ f2sw,
    float* __restrict__ A, float* __restrict__ Bt, float* __restrict__ wout)
{
  const int tid = threadIdx.x;
  const int lane = tid & 63, w = tid >> 6;
  const int i = blockIdx.x;
  const int m = blockIdx.y;
  const int half = blockIdx.z;

  if (i < NN) {
    // ---------------- kanAB path ----------------
    __shared__ float bas[HH * 8];   // dense basis, bas[d*8+k]
    __shared__ float sil[HH];
    const float* q  = (m == 0) ? x   : ((m == 1) ? y   : tg);
    const float* bw = (m == 0) ? xbw : ((m == 1) ? ybw : tbw);
    const float* sw = (m == 0) ? xsw : ((m == 1) ? ysw : tsw);
    const int cb = half * HH;       // weight column base for this half

    if (tid < HH * 8) bas[tid] = 0.0f;
    __syncthreads();
    if (tid < HH) {
      float b[4]; float s; int kb;
      featEval(q[i * HH + tid], s, kb, b);   // features are q[i] for BOTH halves
      sil[tid] = s;
#pragma unroll
      for (int r = 0; r < 4; ++r) {
        const int k = kb + r;
        if ((unsigned)k < 8u) bas[tid * 8 + k] = b[r];
      }
    }
    __syncthreads();

    const float4* bas4 = (const float4*)bas;
    const float4 bb = bas4[lane];
    const float sl = (lane < HH) ? sil[lane] : 0.0f;
#pragma unroll 2
    for (int o = w; o < MM; o += 6) {
      const float4 wv4 = ((const float4*)(sw + ((size_t)(o * 2 * HH + cb) << 3)))[lane];
      const float bwv = (lane < HH) ? bw[o * 2 * HH + cb + lane] : 0.0f;
      float acc = dot4(wv4, bb);
      acc = fmaf(bwv, sl, acc);
      acc = waveReduce(acc);
      if (lane == 0) {
        if (half == 0) A[((size_t)m * NN + i) * MM + o] = acc;
        else           Bt[((size_t)m * MM + o) * NN + i] = acc;
      }
    }
    return;
  }

  // ---------------- fusion path (block (384,0,0) only) ----------------
  if (m != 0 || half != 0) return;
  {
    __shared__ float4 part4[3][8][16];
    __shared__ float sil96[96];
    __shared__ float bas768[96 * 8];
    __shared__ float z1[MM];
    __shared__ float sil2[MM];
    __shared__ float bas400[MM * 8];
    __shared__ float s3[3];

    // phase A: column means (float4-vectorized, 16-way split)
    {
      const int mm = tid >> 7;
      const int sub = tid & 127;
      const int q4 = sub >> 4;
      const int prt = sub & 15;
      const float* src = (mm == 0) ? x : ((mm == 1) ? y : tg);
      const float4* s4 = (const float4*)src;
      float4 a = make_float4(0.f, 0.f, 0.f, 0.f);
      for (int r = prt; r < NN; r += 16) {
        const float4 v = s4[r * 8 + q4];
        a.x += v.x; a.y += v.y; a.z += v.z; a.w += v.w;
      }
      part4[mm][q4][prt] = a;
    }
    for (int idx = tid; idx < 96 * 8; idx += 384) bas768[idx] = 0.0f;
    for (int idx = tid; idx < MM * 8; idx += 384) bas400[idx] = 0.0f;
    __syncthreads();

    // phase B: finish means, build sil96 + dense basis bas768
    if (tid < 96) {
      const int mm = tid >> 5, col = tid & 31;
      const int q4 = col >> 2, comp = col & 3;
      const float* pp = (const float*)&part4[mm][q4][0];
      float v = 0.0f;
#pragma unroll
      for (int prt = 0; prt < 16; ++prt) v += pp[prt * 4 + comp];
      const float fv = v * (1.0f / NN);
      float b[4]; float s; int kb;
      featEval(fv, s, kb, b);
      sil96[tid] = s;
#pragma unroll
      for (int r = 0; r < 4; ++r) {
        const int k = kb + r;
        if ((unsigned)k < 8u) bas768[tid * 8 + k] = b[r];
      }
    }
    __syncthreads();

    // layer 1: 50 outputs, wave-per-output contiguous float4 dot
    {
      const float4* bas4 = (const float4*)bas768;
      for (int o = w; o < MM; o += 6) {
        const float4* sp4 = (const float4*)(f1sw + (size_t)o * (96 * 8));
        float acc = 0.0f;
#pragma unroll
        for (int r = 0; r < 3; ++r)
          acc += dot4(sp4[lane + 64 * r], bas4[lane + 64 * r]);
#pragma unroll
        for (int r = 0; r < 2; ++r) {
          const int e = lane + 64 * r;
          if (e < 96) acc = fmaf(f1bw[o * 96 + e], sil96[e], acc);
        }
        acc = waveReduce(acc);
        if (lane == 0) z1[o] = acc;
      }
    }
    __syncthreads();

    // hidden activation features
    if (tid < MM) {
      float b[4]; float s; int kb;
      featEval(z1[tid], s, kb, b);
      sil2[tid] = s;
#pragma unroll
      for (int r = 0; r < 4; ++r) {
        const int k = kb + r;
        if ((unsigned)k < 8u) bas400[tid * 8 + k] = b[r];
      }
    }
    __syncthreads();

    // layer 2: 3 outputs, one wave each
    if (w < 3) {
      const float4* bas4 = (const float4*)bas400;
      const float4* sp4 = (const float4*)(f2sw + (size_t)w * (MM * 8));
      float acc = 0.0f;
#pragma unroll
      for (int r = 0; r < 2; ++r) {
        const int f = lane + 64 * r;
        if (f < MM * 2) acc += dot4(sp4[f], bas4[f]);
      }
      if (lane < MM) acc = fmaf(f2bw[w * MM + lane], sil2[lane], acc);
      acc = waveReduce(acc);
      if (lane == 0) s3[w] = acc;
    }
    __syncthreads();

    if (tid == 0) {
      const float mx = fmaxf(s3[0], fmaxf(s3[1], s3[2]));
      const float e0 = __expf(s3[0] - mx), e1 = __expf(s3[1] - mx), e2 = __expf(s3[2] - mx);
      const float inv = fastRcp(e0 + e1 + e2);
      wout[0] = e0 * inv; wout[1] = e1 * inv; wout[2] = e2 * inv;
    }
  }
}

// Per-modality layer-2 KAN over all pairs: grid (384 rows, 3 modalities),
// 384 threads (one per column j). Sp[m][i][j] = kanLayer2_m(A_m[i]+B_m[j]).
// The ENTIRE unit g_k(z) = bw_k*silu(z) + spline_k(z) is a single piecewise
// cubic in LDS: 41 real cells on z in [-8.2, 8.2) (spline exact via its
// cardinal-basis coeffs on cells 16..26; silu via Hermite cubic, err ~3e-5),
// cell 0 = zero sentinel (z < -8.2: silu ~ 0), cell 42 = exact-linear
// sentinel (z >= 8.2: silu ~ z, extrapolates for any t). Inner loop per
// unit: ~10 VALU + 1 ds_read_b128, zero transcendentals.
__global__ __launch_bounds__(384) void score_kernel(
    const float* __restrict__ A, const float* __restrict__ Bt,
    const float* __restrict__ x2bw, const float* __restrict__ y2bw, const float* __restrict__ t2bw,
    const float* __restrict__ x2sw, const float* __restrict__ y2sw, const float* __restrict__ t2sw,
    float* __restrict__ Sp)
{
  __shared__ float sA[MM];
  __shared__ float sBW[MM];
  __shared__ float4 herm[43];       // silu Hermite cubic per cell (unit bw)
  __shared__ float4 coefC[MM][43];  // combined per-unit cubic coeffs
  const int tid = threadIdx.x;
  const int i = blockIdx.x;
  const int m = blockIdx.y;
  const float* bsrc = (m == 0) ? x2bw : ((m == 1) ? y2bw : t2bw);
  const float* ssrc = (m == 0) ? x2sw : ((m == 1) ? y2sw : t2sw);

  // phase 1: stage sA/sBW (wave 0) and build silu Hermite table (wave 1)
  if (tid < MM) {
    sA[tid]  = A[((size_t)m * NN + i) * MM + tid];
    sBW[tid] = bsrc[tid];
  }
  if (tid >= 64 && tid < 64 + 43) {
    const int c = tid - 64;
    float4 h;
    if (c == 0) {
      h = make_float4(0.f, 0.f, 0.f, 0.f);            // z < -8.2: silu ~ 0
    } else if (c == 42) {
      h = make_float4(8.2f, 0.4f, 0.f, 0.f);          // z >= 8.2: silu ~ z (linear in t)
    } else {
      const float z0 = -8.2f + (float)(c - 1) * 0.4f;
      const float z1 = z0 + 0.4f;
      const float s0 = fastRcp(1.0f + __expf(-z0));
      const float s1 = fastRcp(1.0f + __expf(-z1));
      const float p0 = z0 * s0, p1 = z1 * s1;
      const float m0 = 0.4f * (s0 * (1.0f + z0 * (1.0f - s0)));
      const float m1 = 0.4f * (s1 * (1.0f + z1 * (1.0f - s1)));
      h.x = p0;
      h.y = m0;
      h.z = 3.0f * (p1 - p0) - 2.0f * m0 - m1;
      h.w = 2.0f * (p0 - p1) + m0 + m1;
    }
    herm[c] = h;
  }
  __syncthreads();

  // phase 2: combined table coefC[k][cc] = bw[k]*herm[cc] + splinecoef(k, cc)
  for (int idx = tid; idx < MM * 43; idx += 384) {
    const int k = idx / 43, cc = idx - k * 43;
    const float bwk = sBW[k];
    const float4 H = herm[cc];
    float4 C = make_float4(bwk * H.x, bwk * H.y, bwk * H.z, bwk * H.w);
    if (cc >= 16 && cc <= 26) {                       // spline support cells
      const int j = cc - 16;                          // 0..10
      float p[4];
#pragma unroll
      for (int r = 0; r < 4; ++r) {
        const int pi = j + r - 3;                     // padded index - 3
        p[r] = ((unsigned)pi < 8u) ? ssrc[k * 8 + pi] : 0.0f;
      }
      C.x += (p[0] + 4.0f * p[1] + p[2]) * (1.0f / 6.0f);
      C.y += (p[2] - p[0]) * 0.5f;
      C.z += (p[0] - 2.0f * p[1] + p[2]) * 0.5f;
      C.w += (p[3] - p[0]) * (1.0f / 6.0f) + (p[1] - p[2]) * 0.5f;
    }
    coefC[k][cc] = C;
  }
  __syncthreads();

#define KAN_EVAL(zz, kk, accv)                                          \
  {                                                                     \
    const float z_ = (zz);                                              \
    const float u_ = fmaf(z_, 2.5f, 20.5f);                             \
    const float fu_ = floorf(u_);                                       \
    const float cu_ = fminf(fmaxf(fu_, -1.0f), 41.0f);                  \
    const float t_ = u_ - cu_;                                          \
    const int cc_ = (int)cu_ + 1;                                       \
    const float4 C_ = coefC[kk][cc_];                                   \
    accv += fmaf(t_, fmaf(t_, fmaf(t_, C_.w, C_.z), C_.y), C_.x);       \
  }

  // main loop: 4-deep Bt prefetch, 2 independent accumulator chains
  const float* BtBase = Bt + (size_t)m * MM * NN + tid;
  float acc0 = 0.0f, acc1 = 0.0f;
  float za = BtBase[0];
  float zb = BtBase[NN];
  float zc = BtBase[2 * NN];
  float zd = BtBase[3 * NN];
#pragma unroll 5
  for (int k = 0; k < MM; k += 2) {
    float ze = 0.0f, zf = 0.0f;
    if (k + 5 < MM) {                       // prefetch 4 ahead
      ze = BtBase[(size_t)(k + 4) * NN];
      zf = BtBase[(size_t)(k + 5) * NN];
    }
    KAN_EVAL(sA[k] + za,     k,     acc0);
    KAN_EVAL(sA[k + 1] + zb, k + 1, acc1);
    za = zc; zb = zd; zc = ze; zd = zf;
  }
#undef KAN_EVAL

  Sp[((size_t)m * NN + i) * NN + tid] = acc0 + acc1;
}

// Row kernel: weighted fuse of 3 score planes + bias, row softmax, @target,
// two final 32->32 KAN layers (relu) via float4 wave-dots. One block per row.
__global__ __launch_bounds__(384) void row_kernel(
    const float* __restrict__ Sp, const float* __restrict__ wv, const float* __restrict__ bias,
    const float* __restrict__ tg,
    const float* __restrict__ l1bw, const float* __restrict__ l1sw,
    const float* __restrict__ l2bw, const float* __restrict__ l2sw,
    float* __restrict__ out)
{
  __shared__ float p[NN];
  __shared__ float redm[6], reds[6];
  __shared__ float part[12][HH];
  __shared__ float ta[HH];
  __shared__ float basF[HH * 8];
  __shared__ float silF[HH];
  __shared__ float y1v[HH];
  const int tid = threadIdx.x;
  const int lane = tid & 63, w = tid >> 6;
  const int i = blockIdx.x;

  float stot = bias[0];
  stot = fmaf(wv[0], Sp[(size_t)i * NN + tid], stot);
  stot = fmaf(wv[1], Sp[((size_t)NN + i) * NN + tid], stot);
  stot = fmaf(wv[2], Sp[((size_t)2 * NN + i) * NN + tid], stot);

  // ---- row softmax ----
  float v = stot;
#pragma unroll
  for (int off = 32; off > 0; off >>= 1) v = fmaxf(v, __shfl_down(v, off));
  if (lane == 0) redm[w] = v;
  __syncthreads();
  float mx = redm[0];
#pragma unroll
  for (int ww = 1; ww < 6; ++ww) mx = fmaxf(mx, redm[ww]);
  const float e = __expf(stot - mx);
  p[tid] = e;
  float sv = e;
#pragma unroll
  for (int off = 32; off > 0; off >>= 1) sv += __shfl_down(sv, off);
  if (lane == 0) reds[w] = sv;
  __syncthreads();
  const float ssum = reds[0] + reds[1] + reds[2] + reds[3] + reds[4] + reds[5];
  const float inv = 1.0f / ssum;

  // ---- target_att row ----
  const int d = tid & 31, g = tid >> 5;
  float acc2 = 0.0f;
  for (int s2 = 0; s2 < 32; ++s2) {
    const int j = g * 32 + s2;
    acc2 = fmaf(p[j], tg[j * HH + d], acc2);
  }
  part[g][d] = acc2;
  if (tid < HH * 8) basF[tid] = 0.0f;
  __syncthreads();
  if (tid < HH) {
    float a = 0.0f;
#pragma unroll
    for (int gg = 0; gg < 12; ++gg) a += part[gg][tid];
    ta[tid] = a * inv;
  }
  __syncthreads();

  // ---- final KAN layer 1 (32 -> 32, relu) via float4 wave-dot ----
  if (tid < HH) {
    float b[4]; float s; int kb;
    featEval(ta[tid], s, kb, b);
    silF[tid] = s;
#pragma unroll
    for (int r = 0; r < 4; ++r) {
      const int k = kb + r;
      if ((unsigned)k < 8u) basF[tid * 8 + k] = b[r];
    }
  }
  __syncthreads();
  {
    const float4 bb = ((const float4*)basF)[lane];
    for (int o = w; o < HH; o += 6) {
      const float4* sp4 = (const float4*)(l1sw + ((size_t)o << 8));
      float acc = dot4(sp4[lane], bb);
      if (lane < HH) acc = fmaf(l1bw[o * HH + lane], silF[lane], acc);
      acc = waveReduce(acc);
      if (lane == 0) y1v[o] = fmaxf(acc, 0.0f);
    }
  }
  __syncthreads();
  if (tid < HH * 8) basF[tid] = 0.0f;
  __syncthreads();
  if (tid < HH) {
    float b[4]; float s; int kb;
    featEval(y1v[tid], s, kb, b);
    silF[tid] = s;
#pragma unroll
    for (int r = 0; r < 4; ++r) {
      const int k = kb + r;
      if ((unsigned)k < 8u) basF[tid * 8 + k] = b[r];
    }
  }
  __syncthreads();
  // ---- final KAN layer 2 (32 -> 32, relu) ----
  {
    const float4 bb = ((const float4*)basF)[lane];
    for (int o = w; o < HH; o += 6) {
      const float4* sp4 = (const float4*)(l2sw + ((size_t)o << 8));
      float acc = dot4(sp4[lane], bb);
      if (lane < HH) acc = fmaf(l2bw[o * HH + lane], silF[lane], acc);
      acc = waveReduce(acc);
      if (lane == 0) out[i * HH + o] = fmaxf(acc, 0.0f);
    }
  }
}

extern "C" void kernel_launch(void* const* d_in, const int* in_sizes, int n_in,
                              void* d_out, int out_size, void* d_ws, size_t ws_size,
                              hipStream_t stream)
{
  const float* x    = (const float*)d_in[0];
  const float* y    = (const float*)d_in[1];
  const float* tg   = (const float*)d_in[2];
  const float* bias = (const float*)d_in[3];
  const float* x1bw = (const float*)d_in[4];
  const float* x1sw = (const float*)d_in[5];
  const float* x2bw = (const float*)d_in[6];
  const float* x2sw = (const float*)d_in[7];
  const float* y1bw = (const float*)d_in[8];
  const float* y1sw = (const float*)d_in[9];
  const float* y2bw = (const float*)d_in[10];
  const float* y2sw = (const float*)d_in[11];
  const float* t1bw = (const float*)d_in[12];
  const float* t1sw = (const float*)d_in[13];
  const float* t2bw = (const float*)d_in[14];
  const float* t2sw = (const float*)d_in[15];
  const float* f1bw = (const float*)d_in[16];
  const float* f1sw = (const float*)d_in[17];
  const float* f2bw = (const float*)d_in[18];
  const float* f2sw = (const float*)d_in[19];
  const float* l1bw = (const float*)d_in[20];
  const float* l1sw = (const float*)d_in[21];
  const float* l2bw = (const float*)d_in[22];
  const float* l2sw = (const float*)d_in[23];
  float* out = (float*)d_out;

  float* ws = (float*)d_ws;
  float* A  = ws;                          // [3][384][50]
  float* Bt = ws + 3 * NN * MM;            // [3][50][384]
  float* Sp = ws + 6 * NN * MM;            // [3][384][384]
  float* wv = Sp + 3 * NN * NN;            // [3]

  stageA_kernel<<<dim3(NN + 1, 3, 2), 384, 0, stream>>>(
      x, y, tg, x1bw, x1sw, y1bw, y1sw, t1bw, t1sw,
      f1bw, f1sw, f2bw, f2sw, A, Bt, wv);
  score_kernel<<<dim3(NN, 3), 384, 0, stream>>>(A, Bt, x2bw, y2bw, t2bw,
                                                x2sw, y2sw, t2sw, Sp);
  row_kernel<<<NN, 384, 0, stream>>>(Sp, wv, bias, tg, l1bw, l1sw, l2bw, l2sw, out);
}